// Round 11
// baseline (90.852 us; speedup 1.0000x reference)
//
#include <hip/hip_runtime.h>
#include <math.h>

// ---------------------------------------------------------------------------
// Model (validated rounds 1-10, absmax 7.6e-6):
//   cov_t = p_t * I ;  p' = A2*p^2 + B1*p + C0  (batch-independent chain)
//   s_t = c*p_t + d ;  m_t = 1 + DT*(ad - c*s_t) ;  Phi_t = m_t - i*kap
//   G_t = prod_{u<t} Phi_u (fp64) ;  u_k = s_k/G_{k+1} ;  v_t = (c*DT)*G_t
//   out_t = v_t (*) (x0 + S_t),  S_t = exclusive complex prefix of u_k (*) dy_k
// Round-11: SINGLE KERNEL. Fabric-bound regime established (L3 is memory-
// side: FETCH=0 replays run same duration). Only non-fabric cost left was
// the setup dispatch (~5us incl. gap). Every block now computes u/v tables
// redundantly (VALU 77% idle -> hidden), p-chain per-thread in registers
// (warm-up 8*(tid&7) + 8 kept steps, bit-identical sequence), u/v exchanged
// via 32KB LDS. dy loads issued first -> HBM latency hides under setup.
// ---------------------------------------------------------------------------

typedef float nfloat4 __attribute__((ext_vector_type(4)));

template <int CTRL, int ROW_MASK>
__device__ __forceinline__ float dpp0(float x) {
    return __int_as_float(__builtin_amdgcn_update_dpp(
        0, __float_as_int(x), CTRL, ROW_MASK, 0xf, false));
}

// wave64 inclusive add-scan, VALU-only (LLVM AtomicOptimizer idiom)
__device__ __forceinline__ float wave_scan_add(float x) {
    x += dpp0<0x111, 0xf>(x);   // row_shr:1
    x += dpp0<0x112, 0xf>(x);   // row_shr:2
    x += dpp0<0x114, 0xf>(x);   // row_shr:4
    x += dpp0<0x118, 0xf>(x);   // row_shr:8
    x += dpp0<0x142, 0xa>(x);   // row_bcast:15 -> rows 1,3
    x += dpp0<0x143, 0xc>(x);   // row_bcast:31 -> rows 2,3
    return x;
}

__global__ __launch_bounds__(256) void fused_kernel(
    const float* __restrict__ dy,
    const float* __restrict__ x0,
    const float* __restrict__ cov0,
    const float* __restrict__ coeffs,
    float* __restrict__ out,
    int T)
{
    __shared__ float4 uL[1024];     // 16 KiB  u table (complex pairs)
    __shared__ float4 vL[1024];     // 16 KiB  v table
    __shared__ float3 Ee[32];       // chunk-end (p,d,h)
    __shared__ float  Del[32];      // true_start - guess per chunk
    __shared__ double2 dagg[4];     // fp64 scan wave aggregates
    __shared__ float2 aggs[4][4];   // fused-scan [stripe][wave]

    const int tid  = threadIdx.x;
    const int lane = tid & 63;
    const int wid  = tid >> 6;
    const int b    = blockIdx.x;

    // ---- issue dy (HBM) loads immediately; latency hides under setup ----
    const float4* __restrict__ dyv =
        reinterpret_cast<const float4*>(dy + (size_t)b * T * 2);
    nfloat4* __restrict__ outv =
        reinterpret_cast<nfloat4*>(out + (size_t)b * T * 2);
    float4 d4[4];
#pragma unroll
    for (int j = 0; j < 4; ++j) d4[j] = dyv[j * 256 + tid];
    const float x0r = x0[2 * b];
    const float x0i = x0[2 * b + 1];

    // ---- constants ----
    const double cdD = sqrt(4.0 * 0.8 * 0.5);     // C diag
    const double ddD = 0.3 * (2.0 + 0.5) + 0.5;   // D diag
    const double adD = -0.5 * 0.3;                // A diag
    const double aD  = -1e-3 * (cdD * cdD);
    const double bD  = 1.0 + 1e-3 * (2.0 * adD - 2.0 * cdD * ddD);
    const double cDc = 1e-3 * (ddD - ddD * ddD);
    const float cC   = (float)cdD;
    const float dcon = (float)ddD;
    const float ad   = (float)adD;
    const float A2   = (float)aD;
    const float B1   = (float)bD;
    const float C0   = (float)cDc;
    const double kap = 1e-3 * (double)coeffs[0];
    const double cdt = cdD * 1e-3;
    const double beta = bD - 1.0;
    const float pstar = (float)((-beta - sqrt(beta * beta - 4.0 * aD * cDc)) / (2.0 * aD));

    // ---- p-chain: each thread runs its chunk from the guess ----
    // chunk c = tid>>3, slot qp = tid&7; warm-up 8*qp steps, keep 8.
    const int c  = tid >> 3;
    const int qp = tid & 7;
    float p   = (c == 0) ? cov0[0] : pstar;
    float dch = 1.0f, hch = 0.0f;
    for (int i = 0; i < 8 * qp; ++i) {
        float lam = fmaf(2.0f * A2, p, B1);
        hch = fmaf(lam, hch, A2 * dch * dch);
        dch = lam * dch;
        p   = fmaf(fmaf(A2, p, B1), p, C0);
    }
    float kp[8], kd[8], kh[8];
#pragma unroll
    for (int e = 0; e < 8; ++e) {
        kp[e] = p; kd[e] = dch; kh[e] = hch;
        float lam = fmaf(2.0f * A2, p, B1);
        hch = fmaf(lam, hch, A2 * dch * dch);
        dch = lam * dch;
        p   = fmaf(fmaf(A2, p, B1), p, C0);
    }
    if (qp == 7) Ee[c] = make_float3(p, dch, hch);
    __syncthreads();

    if (tid == 0) {
        float D = 0.0f;
        Del[0] = 0.0f;
        for (int cc = 0; cc < 31; ++cc) {
            float3 e = Ee[cc];
            float tn = e.x + D * fmaf(e.z, D, e.y);   // true start of chunk cc+1
            D = tn - pstar;
            Del[cc + 1] = D;
        }
    }
    __syncthreads();
    const float Dl = Del[c];

    // ---- corrected p -> (m,s); fp64 Phi product over this thread's 8 ----
    float sv[8], mv[8];
    double Pr = 1.0, Pi = 0.0;
#pragma unroll
    for (int e = 0; e < 8; ++e) {
        float pc = kp[e] + Dl * fmaf(kh[e], Dl, kd[e]);
        float s  = fmaf(cC, pc, dcon);
        float m  = fmaf(1e-3f, fmaf(-cC, s, ad), 1.0f);
        sv[e] = s; mv[e] = m;
        double nr = (double)m * Pr + kap * Pi;   // *(m - i*kap)
        double ni = (double)m * Pi - kap * Pr;
        Pr = nr; Pi = ni;
    }

    // ---- fp64 wave inclusive scan (complex product) + block combine ----
    double vr = Pr, vi = Pi;
#pragma unroll
    for (int delta = 1; delta < 64; delta <<= 1) {
        double ur = __shfl_up(vr, delta);
        double ui = __shfl_up(vi, delta);
        if (lane >= delta) {
            double nr = ur * vr - ui * vi;
            double ni = ur * vi + ui * vr;
            vr = nr; vi = ni;
        }
    }
    if (lane == 63) dagg[wid] = make_double2(vr, vi);
    double exr = __shfl_up(vr, 1), exi = __shfl_up(vi, 1);
    if (lane == 0) { exr = 1.0; exi = 0.0; }
    __syncthreads();

    double br = 1.0, bi = 0.0;
    for (int w = 0; w < wid; ++w) {
        double2 a = dagg[w];
        double nr = br * a.x - bi * a.y;
        double ni = br * a.y + bi * a.x;
        br = nr; bi = ni;
    }
    double Gr = br * exr - bi * exi;   // G at t = 8*tid
    double Gi = br * exi + bi * exr;

    // ---- u/v for this thread's 8 steps -> LDS (contiguous write) ----
    float uo[16], vo[16];
#pragma unroll
    for (int e = 0; e < 8; ++e) {
        vo[2 * e]     = (float)(cdt * Gr);
        vo[2 * e + 1] = (float)(cdt * Gi);
        double nr = (double)mv[e] * Gr + kap * Gi;   // G_{t+1}
        double ni = (double)mv[e] * Gi - kap * Gr;
        Gr = nr; Gi = ni;
        double inv = 1.0 / (Gr * Gr + Gi * Gi);
        uo[2 * e]     = (float)( (double)sv[e] * Gr * inv);  // s*conj(G)/|G|^2
        uo[2 * e + 1] = (float)(-(double)sv[e] * Gi * inv);
    }
#pragma unroll
    for (int j = 0; j < 4; ++j) {
        uL[4 * tid + j] = make_float4(uo[4*j], uo[4*j+1], uo[4*j+2], uo[4*j+3]);
        vL[4 * tid + j] = make_float4(vo[4*j], vo[4*j+1], vo[4*j+2], vo[4*j+3]);
    }
    __syncthreads();

    // ================= fused phase (R10 structure, u/v from LDS) =========
    float2 q[8], qq[4];
#pragma unroll
    for (int j = 0; j < 4; ++j) {
        float4 d = d4[j];
        float4 u = uL[j * 256 + tid];   // strided read, conflict-free b128
        q[2*j].x   = fmaf(u.x, d.x, -(u.y * d.y));
        q[2*j].y   = fmaf(u.x, d.y,  (u.y * d.x));
        q[2*j+1].x = fmaf(u.z, d.z, -(u.w * d.w));
        q[2*j+1].y = fmaf(u.z, d.w,  (u.w * d.z));
        qq[j].x = q[2*j].x + q[2*j+1].x;
        qq[j].y = q[2*j].y + q[2*j+1].y;
    }

    // 4 wave-level inclusive scans (complex add) — DPP, VALU-only
    float2 incl[4];
#pragma unroll
    for (int j = 0; j < 4; ++j) {
        incl[j].x = wave_scan_add(qq[j].x);
        incl[j].y = wave_scan_add(qq[j].y);
    }
    if (lane == 63) {
#pragma unroll
        for (int j = 0; j < 4; ++j) aggs[j][wid] = incl[j];
    }
    __syncthreads();

    float2 run = make_float2(x0r, x0i);
    float2 Sst[4];
#pragma unroll
    for (int j = 0; j < 4; ++j) {
        float2 wp  = make_float2(0.f, 0.f);
        float2 tot = make_float2(0.f, 0.f);
#pragma unroll
        for (int w = 0; w < 4; ++w) {
            float2 a = aggs[j][w];
            tot.x += a.x; tot.y += a.y;
            if (w < wid) { wp.x += a.x; wp.y += a.y; }
        }
        // exclusive in-wave prefix = inclusive - own stripe sum (1 ulp)
        Sst[j].x = run.x + wp.x + (incl[j].x - qq[j].x);
        Sst[j].y = run.y + wp.y + (incl[j].y - qq[j].y);
        run.x += tot.x; run.y += tot.y;
    }

    // emission: stripe j covers timesteps 2L, 2L+1 at L = j*256 + tid
#pragma unroll
    for (int j = 0; j < 4; ++j) {
        float4 w = vL[j * 256 + tid];
        float2 S = Sst[j];
        nfloat4 o;
        o.x = fmaf(w.x, S.x, -(w.y * S.y));
        o.y = fmaf(w.x, S.y,  (w.y * S.x));
        S.x += q[2*j].x; S.y += q[2*j].y;
        o.z = fmaf(w.z, S.x, -(w.w * S.y));
        o.w = fmaf(w.z, S.y,  (w.w * S.x));
        __builtin_nontemporal_store(o, &outv[j * 256 + tid]);
    }
}

extern "C" void kernel_launch(void* const* d_in, const int* in_sizes, int n_in,
                              void* d_out, int out_size, void* d_ws, size_t ws_size,
                              hipStream_t stream)
{
    const float* dy     = (const float*)d_in[0];
    const float* x0     = (const float*)d_in[1];
    const float* cov0   = (const float*)d_in[2];
    const float* coeffs = (const float*)d_in[3];
    float* out = (float*)d_out;

    const int B = in_sizes[1] / 2;           // 8192
    const int T = in_sizes[0] / in_sizes[1]; // 2048 (kernel assumes 2048)

    fused_kernel<<<B, 256, 0, stream>>>(dy, x0, cov0, coeffs, out, T);
}

// Round 12
// 49.301 us; speedup vs baseline: 1.8428x; 1.8428x over previous
//
#include <hip/hip_runtime.h>
#include <math.h>

// ---------------------------------------------------------------------------
// Model (validated rounds 1-11, absmax 7.6e-6):
//   cov_t = p_t * I ;  p' = A2*p^2 + B1*p + C0  (batch-independent chain)
//   s_t = c*p_t + d ;  m_t = 1 + DT*(ad - c*s_t) ;  Phi_t = m_t - i*kap
//   G_t = prod_{u<t} Phi_u (fp64) ;  u_k = s_k/G_{k+1} ;  v_t = (c*DT)*G_t
//   out_t = v_t (*) (x0 + S_t),  S_t = exclusive complex prefix of u_k (*) dy_k
// Round-12: REVERT to R8 (best measured, 49.0us). R11's per-block setup
// fusion regressed to 90.9us (VALUBusy 73%, 2.7e7 LDS bank conflicts).
// Converged configuration per A/B matrix R7-R11:
//   * two kernels: tiny setup (u/v tables) + fused (1 row / 256-thr block)
//   * nt stores (+2.5us: keeps out-stream out of L2/L3, dy stays L3-resident)
//   * DPP VALU-only scan; occupancy irrelevant (25% vs 70% identical)
// Steady-state fabric traffic ~260MB / ~44us fused = ~5.9TB/s = ~94% of the
// 6.3TB/s empirical ceiling -> fabric roofline.
// ---------------------------------------------------------------------------

typedef float nfloat4 __attribute__((ext_vector_type(4)));

template <int CTRL, int ROW_MASK>
__device__ __forceinline__ float dpp0(float x) {
    return __int_as_float(__builtin_amdgcn_update_dpp(
        0, __float_as_int(x), CTRL, ROW_MASK, 0xf, false));
}

// wave64 inclusive add-scan, VALU-only (LLVM AtomicOptimizer idiom)
__device__ __forceinline__ float wave_scan_add(float x) {
    x += dpp0<0x111, 0xf>(x);   // row_shr:1
    x += dpp0<0x112, 0xf>(x);   // row_shr:2
    x += dpp0<0x114, 0xf>(x);   // row_shr:4
    x += dpp0<0x118, 0xf>(x);   // row_shr:8
    x += dpp0<0x142, 0xa>(x);   // row_bcast:15 -> rows 1,3
    x += dpp0<0x143, 0xc>(x);   // row_bcast:31 -> rows 2,3
    return x;
}

__global__ __launch_bounds__(256) void setup_kernel(
    const float* __restrict__ cov0,
    const float* __restrict__ coeffs,
    float* __restrict__ utab,   // 2048 complex, linear float4 (2 steps each)
    float* __restrict__ vtab)
{
    __shared__ float php[2048];   // guessed chain p-hat
    __shared__ float phd[2048];   // d p-hat / d start
    __shared__ float phh[2048];   // second-order coefficient chain
    __shared__ float3 Ee[32];     // end-of-chunk (p,d,h)
    __shared__ float Del[32];     // true_start - guess per chunk
    __shared__ double2 agg[4];

    const double cdD = sqrt(4.0 * 0.8 * 0.5);     // C diag
    const double ddD = 0.3 * (2.0 + 0.5) + 0.5;   // D diag
    const double adD = -0.5 * 0.3;                // A diag
    const double aD  = -1e-3 * (cdD * cdD);
    const double bD  = 1.0 + 1e-3 * (2.0 * adD - 2.0 * cdD * ddD);
    const double cDc = 1e-3 * (ddD - ddD * ddD);

    const float cC   = (float)cdD;
    const float dcon = (float)ddD;
    const float ad   = (float)adD;
    const float A2   = (float)aD;
    const float B1   = (float)bD;
    const float C0   = (float)cDc;

    const double kap = 1e-3 * (double)coeffs[0];
    const double cdt = cdD * 1e-3;

    const int tid  = threadIdx.x;
    const int lane = tid & 63;
    const int wid  = tid >> 6;

    const double beta = bD - 1.0;
    const float pstar = (float)((-beta - sqrt(beta * beta - 4.0 * aD * cDc)) / (2.0 * aD));

    // --- parallel p-chain: 32 chunks x 64 steps, 2nd-order perturbation ---
    if (tid < 32) {
        float p   = (tid == 0) ? cov0[0] : pstar;
        float dch = 1.0f, hch = 0.0f;
        const int base = tid * 64;
        for (int i = 0; i < 64; ++i) {
            php[base + i] = p;
            phd[base + i] = dch;
            phh[base + i] = hch;
            float lam = fmaf(2.0f * A2, p, B1);
            hch = fmaf(lam, hch, A2 * dch * dch);
            dch = lam * dch;
            p   = fmaf(fmaf(A2, p, B1), p, C0);
        }
        Ee[tid] = make_float3(p, dch, hch);
    }
    __syncthreads();
    if (tid == 0) {
        float D = 0.0f;
        Del[0] = 0.0f;
        for (int c = 0; c < 31; ++c) {
            float3 e = Ee[c];
            float tn = e.x + D * fmaf(e.z, D, e.y);
            D = tn - pstar;
            Del[c + 1] = D;
        }
    }
    __syncthreads();

    // --- corrected p -> (m,s), fp64 Phi product over this thread's 8 steps ---
    const float Dl = Del[tid >> 3];
    float sv[8], mv[8];
    double Pr = 1.0, Pi = 0.0;
#pragma unroll
    for (int e = 0; e < 8; ++e) {
        int t = tid * 8 + e;
        float p = php[t] + Dl * fmaf(phh[t], Dl, phd[t]);
        float s = fmaf(cC, p, dcon);
        float m = fmaf(1e-3f, fmaf(-cC, s, ad), 1.0f);
        sv[e] = s; mv[e] = m;
        double nr = (double)m * Pr + kap * Pi;
        double ni = (double)m * Pi - kap * Pr;
        Pr = nr; Pi = ni;
    }

    // wave inclusive scan (complex product, fp64) — setup only, keep shfl
    double vr = Pr, vi = Pi;
#pragma unroll
    for (int delta = 1; delta < 64; delta <<= 1) {
        double ur = __shfl_up(vr, delta);
        double ui = __shfl_up(vi, delta);
        if (lane >= delta) {
            double nr = ur * vr - ui * vi;
            double ni = ur * vi + ui * vr;
            vr = nr; vi = ni;
        }
    }
    if (lane == 63) agg[wid] = make_double2(vr, vi);
    double exr = __shfl_up(vr, 1), exi = __shfl_up(vi, 1);
    if (lane == 0) { exr = 1.0; exi = 0.0; }
    __syncthreads();

    double br = 1.0, bi = 0.0;
    for (int w = 0; w < wid; ++w) {
        double2 a = agg[w];
        double nr = br * a.x - bi * a.y;
        double ni = br * a.y + bi * a.x;
        br = nr; bi = ni;
    }
    double Gr = br * exr - bi * exi;
    double Gi = br * exi + bi * exr;

    float uo[16], vo[16];
#pragma unroll
    for (int e = 0; e < 8; ++e) {
        vo[2 * e]     = (float)(cdt * Gr);
        vo[2 * e + 1] = (float)(cdt * Gi);
        double nr = (double)mv[e] * Gr + kap * Gi;
        double ni = (double)mv[e] * Gi - kap * Gr;
        Gr = nr; Gi = ni;
        double inv = 1.0 / (Gr * Gr + Gi * Gi);
        uo[2 * e]     = (float)( (double)sv[e] * Gr * inv);
        uo[2 * e + 1] = (float)(-(double)sv[e] * Gi * inv);
    }

    float4* up4 = (float4*)utab;
    float4* vp4 = (float4*)vtab;
#pragma unroll
    for (int j = 0; j < 4; ++j) {
        up4[4 * tid + j] = make_float4(uo[4*j], uo[4*j+1], uo[4*j+2], uo[4*j+3]);
        vp4[4 * tid + j] = make_float4(vo[4*j], vo[4*j+1], vo[4*j+2], vo[4*j+3]);
    }
}

__global__ __launch_bounds__(256, 8) void fused_kernel(
    const float* __restrict__ dy,
    const float* __restrict__ x0,
    const float* __restrict__ utab,
    const float* __restrict__ vtab,
    float* __restrict__ out,
    int T)
{
    __shared__ float2 aggs[4][4];   // [stripe][wave]

    const int tid  = threadIdx.x;
    const int lane = tid & 63;
    const int wid  = tid >> 6;
    const int b    = blockIdx.x;

    const float4* __restrict__ up4 = reinterpret_cast<const float4*>(utab);
    const float4* __restrict__ vp4 = reinterpret_cast<const float4*>(vtab);
    const float4* __restrict__ dyv =
        reinterpret_cast<const float4*>(dy + (size_t)b * T * 2);
    nfloat4* __restrict__ outv =
        reinterpret_cast<nfloat4*>(out + (size_t)b * T * 2);

    // load dy + u, fold immediately into products q ; per-stripe pair sums
    float2 q[8], qq[4];
#pragma unroll
    for (int j = 0; j < 4; ++j) {
        float4 d = dyv[j * 256 + tid];
        float4 u = up4[j * 256 + tid];
        q[2*j].x   = fmaf(u.x, d.x, -(u.y * d.y));
        q[2*j].y   = fmaf(u.x, d.y,  (u.y * d.x));
        q[2*j+1].x = fmaf(u.z, d.z, -(u.w * d.w));
        q[2*j+1].y = fmaf(u.z, d.w,  (u.w * d.z));
        qq[j].x = q[2*j].x + q[2*j+1].x;
        qq[j].y = q[2*j].y + q[2*j+1].y;
    }

    // 4 wave-level inclusive scans (complex add) — DPP, VALU-only
    float2 incl[4];
#pragma unroll
    for (int j = 0; j < 4; ++j) {
        incl[j].x = wave_scan_add(qq[j].x);
        incl[j].y = wave_scan_add(qq[j].y);
    }
    if (lane == 63) {
#pragma unroll
        for (int j = 0; j < 4; ++j) aggs[j][wid] = incl[j];
    }
    __syncthreads();

    float2 run = make_float2(x0[2 * b], x0[2 * b + 1]);
    float2 Sst[4];
#pragma unroll
    for (int j = 0; j < 4; ++j) {
        float2 wp  = make_float2(0.f, 0.f);
        float2 tot = make_float2(0.f, 0.f);
#pragma unroll
        for (int w = 0; w < 4; ++w) {
            float2 a = aggs[j][w];
            tot.x += a.x; tot.y += a.y;
            if (w < wid) { wp.x += a.x; wp.y += a.y; }
        }
        // exclusive in-wave prefix = inclusive - own stripe sum (1 ulp)
        Sst[j].x = run.x + wp.x + (incl[j].x - qq[j].x);
        Sst[j].y = run.y + wp.y + (incl[j].y - qq[j].y);
        run.x += tot.x; run.y += tot.y;
    }

    // emission: stripe j covers timesteps 2L, 2L+1 at L = j*256 + tid
#pragma unroll
    for (int j = 0; j < 4; ++j) {
        float4 w = vp4[j * 256 + tid];
        float2 S = Sst[j];
        nfloat4 o;
        o.x = fmaf(w.x, S.x, -(w.y * S.y));
        o.y = fmaf(w.x, S.y,  (w.y * S.x));
        S.x += q[2*j].x; S.y += q[2*j].y;
        o.z = fmaf(w.z, S.x, -(w.w * S.y));
        o.w = fmaf(w.z, S.y,  (w.w * S.x));
        __builtin_nontemporal_store(o, &outv[j * 256 + tid]);
    }
}

extern "C" void kernel_launch(void* const* d_in, const int* in_sizes, int n_in,
                              void* d_out, int out_size, void* d_ws, size_t ws_size,
                              hipStream_t stream)
{
    const float* dy     = (const float*)d_in[0];
    const float* x0     = (const float*)d_in[1];
    const float* cov0   = (const float*)d_in[2];
    const float* coeffs = (const float*)d_in[3];
    float* out = (float*)d_out;

    const int B = in_sizes[1] / 2;           // 8192
    const int T = in_sizes[0] / in_sizes[1]; // 2048 (setup assumes 2048)

    float* utab = (float*)d_ws;              // 2048 complex = 16 KiB
    float* vtab = utab + 4096;               // 2048 complex = 16 KiB

    setup_kernel<<<1, 256, 0, stream>>>(cov0, coeffs, utab, vtab);
    fused_kernel<<<B, 256, 0, stream>>>(dy, x0, utab, vtab, out, T);
}